// Round 5
// baseline (238.905 us; speedup 1.0000x reference)
//
#include <hip/hip_runtime.h>

#define NODES 128
#define NFEAT 256
#define BATCH 512
#define KTOT  (NODES * NFEAT)   // 32768, stage-3 K
#define SPLIT 128               // stage-3 split-K factor
#define KCH   (KTOT / SPLIT)    // 256 per chunk

typedef __bf16 bf16_t;
typedef bf16_t bf16x8 __attribute__((ext_vector_type(8)));
typedef float  f32x4  __attribute__((ext_vector_type(4)));

#define BK    32
#define LDK   40     // bf16 LDS row stride for 32-wide tiles (80B)
#define BK2   64
#define LDK2  72     // bf16 LDS row stride for 64-wide tiles (144B)
#define LDM   136    // Sb row stride
#define TILE  128

__device__ __forceinline__ bf16x8 cvt8(const float4 a, const float4 b) {
    bf16x8 t;
    t[0] = (bf16_t)a.x; t[1] = (bf16_t)a.y; t[2] = (bf16_t)a.z; t[3] = (bf16_t)a.w;
    t[4] = (bf16_t)b.x; t[5] = (bf16_t)b.y; t[6] = (bf16_t)b.z; t[7] = (bf16_t)b.w;
    return t;
}

// ---- fp32 128x32 tile: reg-load / LDS-store (2-barrier pipeline) ----
struct XT { float4 v[4]; };
__device__ __forceinline__ void xload(const float* __restrict__ src, int ld, int k0,
                                      int tid, XT& t) {
#pragma unroll
    for (int i = 0; i < 2; i++) {
        int f = tid + i * 256, r = f >> 2, c = f & 3;
        t.v[2 * i]     = *(const float4*)(src + (size_t)r * ld + k0 + c * 8);
        t.v[2 * i + 1] = *(const float4*)(src + (size_t)r * ld + k0 + c * 8 + 4);
    }
}
__device__ __forceinline__ void xstore(bf16_t* __restrict__ dst, int tid, const XT& t) {
#pragma unroll
    for (int i = 0; i < 2; i++) {
        int f = tid + i * 256, r = f >> 2, c = f & 3;
        *(bf16x8*)(dst + r * LDK + c * 8) = cvt8(t.v[2 * i], t.v[2 * i + 1]);
    }
}

// ---- fp32 128x64 tile (k_out B) ----
struct XT2 { float4 v[8]; };
__device__ __forceinline__ void xload2(const float* __restrict__ src, int ld, int k0,
                                       int tid, XT2& t) {
#pragma unroll
    for (int i = 0; i < 4; i++) {
        int f = tid + i * 256, r = f >> 3, c = f & 7;   // c = 8-float pair index
        t.v[2 * i]     = *(const float4*)(src + (size_t)r * ld + k0 + c * 8);
        t.v[2 * i + 1] = *(const float4*)(src + (size_t)r * ld + k0 + c * 8 + 4);
    }
}
__device__ __forceinline__ void xstore2(bf16_t* __restrict__ dst, int tid, const XT2& t) {
#pragma unroll
    for (int i = 0; i < 4; i++) {
        int f = tid + i * 256, r = f >> 3, c = f & 7;
        *(bf16x8*)(dst + r * LDK2 + c * 8) = cvt8(t.v[2 * i], t.v[2 * i + 1]);
    }
}

// ---- bf16 128x64 tile (k_out A, K-contiguous source) ----
struct AT2 { bf16x8 v[4]; };
__device__ __forceinline__ void aload2(const bf16_t* __restrict__ src, int ld, int k0,
                                       int tid, AT2& t) {
#pragma unroll
    for (int i = 0; i < 4; i++) {
        int f = tid + i * 256, r = f >> 3, c = f & 7;
        t.v[i] = *(const bf16x8*)(src + (size_t)r * ld + k0 + c * 8);
    }
}
__device__ __forceinline__ void astore2(bf16_t* __restrict__ dst, int tid, const AT2& t) {
#pragma unroll
    for (int i = 0; i < 4; i++) {
        int f = tid + i * 256, r = f >> 3, c = f & 7;
        *(bf16x8*)(dst + r * LDK2 + c * 8) = t.v[i];
    }
}

// ---- pre-transpose gcn_w[k][g] -> wT[g][k] bf16 ----
__global__ __launch_bounds__(256)
void k_wt(const float* __restrict__ w, bf16_t* __restrict__ wT) {
    const int g0 = blockIdx.x * 4;
    const int k  = threadIdx.x;
    const float4 v = *(const float4*)(w + (size_t)k * NFEAT + g0);
    wT[(size_t)(g0 + 0) * NFEAT + k] = (bf16_t)v.x;
    wT[(size_t)(g0 + 1) * NFEAT + k] = (bf16_t)v.y;
    wT[(size_t)(g0 + 2) * NFEAT + k] = (bf16_t)v.z;
    wT[(size_t)(g0 + 3) * NFEAT + k] = (bf16_t)v.w;
}

// ---- init: out slot0 = fc_b, slot1 = x[:,0,:] ----
__global__ __launch_bounds__(256)
void k_init(const float* __restrict__ fc_b, const float* __restrict__ x,
            float* __restrict__ out) {
    const int g = blockIdx.x * 256 + threadIdx.x;
    const int o = g & (NFEAT - 1), b = g >> 8;
    out[g] = fc_b[o];
    out[BATCH * NFEAT + g] = x[(size_t)b * NODES * NFEAT + o];
}

// ---- fin: slot2 = slot0 (after all k_out atomics) ----
__global__ __launch_bounds__(256)
void k_fin(float* __restrict__ out) {
    const int g = blockIdx.x * 256 + threadIdx.x;
    out[2 * BATCH * NFEAT + g] = out[g];
}

// ---- fused stages 1+2: dist-2 reg prefetch, 3 blocks/CU ----
__global__ __launch_bounds__(256, 3)
void k_fused12(const float* __restrict__ x, const float* __restrict__ adj,
               const bf16_t* __restrict__ wT, const float* __restrict__ gcn_b,
               bf16_t* __restrict__ mid) {
    __shared__ __align__(16) bf16_t As[TILE * LDK];   // 10.2 KB
    __shared__ __align__(16) bf16_t Sb[TILE * LDM];   // 34.8 KB
    const int n0  = blockIdx.x * TILE;   // g-tile (0 or 128)
    const int b   = blockIdx.y;
    const int tid = threadIdx.x;
    const int lane = tid & 63, w = tid >> 6, wm = w & 1, wn = w >> 1;
    const int l15 = lane & 15, q = lane >> 4;
    const float* xb   = x   + (size_t)b * NODES * NFEAT;
    const float* adjb = adj + (size_t)b * NODES * NODES;

    const bf16_t* wrow[4];
#pragma unroll
    for (int j = 0; j < 4; j++)
        wrow[j] = wT + (size_t)(n0 + wn * 64 + j * 16 + l15) * NFEAT + q * 8;

    // ---- stage 1: S = x[b] @ W  (K=256, 8 iters, prefetch distance 2) ----
    f32x4 acc[4][4] = {};
    {
        XT r0, rn, r2;
        xload(xb, NFEAT, 0, tid, r0);
        xload(xb, NFEAT, BK, tid, rn);
        bf16x8 bcur[4], bnxt[4];
#pragma unroll
        for (int j = 0; j < 4; j++) bcur[j] = *(const bf16x8*)(wrow[j]);
        xstore(As, tid, r0);
        __syncthreads();
        for (int k0 = 0; k0 < NFEAT; k0 += BK) {
            const bool in1 = (k0 + BK)  < NFEAT;
            const bool in2 = (k0 + 2*BK) < NFEAT;
            if (in2) xload(xb, NFEAT, k0 + 2*BK, tid, r2);   // dist-2 HBM prefetch
            const int knc = in1 ? k0 + BK : 0;
#pragma unroll
            for (int j = 0; j < 4; j++) bnxt[j] = *(const bf16x8*)(wrow[j] + knc);
            bf16x8 a[4];
#pragma unroll
            for (int i = 0; i < 4; i++)
                a[i] = *(const bf16x8*)(As + (wm * 64 + i * 16 + l15) * LDK + q * 8);
#pragma unroll
            for (int i = 0; i < 4; i++)
#pragma unroll
                for (int j = 0; j < 4; j++)
                    acc[i][j] = __builtin_amdgcn_mfma_f32_16x16x32_bf16(a[i], bcur[j], acc[i][j], 0, 0, 0);
            __syncthreads();
            if (in1) xstore(As, tid, rn);
            rn = r2;
#pragma unroll
            for (int j = 0; j < 4; j++) bcur[j] = bnxt[j];
            __syncthreads();
        }
    }

    // stage-2 tiles 0,1 in flight while writing Sb
    XT a0, a1, a2;
    xload(adjb, NODES, 0, tid, a0);
    xload(adjb, NODES, BK, tid, a1);
#pragma unroll
    for (int i = 0; i < 4; i++)
#pragma unroll
        for (int j = 0; j < 4; j++)
#pragma unroll
            for (int r = 0; r < 4; r++) {
                int m = wm * 64 + i * 16 + q * 4 + r;
                int g = wn * 64 + j * 16 + l15;
                Sb[g * LDM + m] = (bf16_t)acc[i][j][r];
            }
    __syncthreads();               // stage-1 As reads done + Sb visible
    xstore(As, tid, a0);
    __syncthreads();

    // ---- stage 2: mid = adj[b] @ S  (K=128, 4 iters, dist-2) ----
    f32x4 acc2[4][4] = {};
    for (int k0 = 0; k0 < NODES; k0 += BK) {
        const bool in1 = (k0 + BK)   < NODES;
        const bool in2 = (k0 + 2*BK) < NODES;
        if (in2) xload(adjb, NODES, k0 + 2*BK, tid, a2);
        bf16x8 a[4], bb[4];
#pragma unroll
        for (int i = 0; i < 4; i++)
            a[i] = *(const bf16x8*)(As + (wm * 64 + i * 16 + l15) * LDK + q * 8);
#pragma unroll
        for (int j = 0; j < 4; j++)
            bb[j] = *(const bf16x8*)(Sb + (wn * 64 + j * 16 + l15) * LDM + k0 + q * 8);
#pragma unroll
        for (int i = 0; i < 4; i++)
#pragma unroll
            for (int j = 0; j < 4; j++)
                acc2[i][j] = __builtin_amdgcn_mfma_f32_16x16x32_bf16(a[i], bb[j], acc2[i][j], 0, 0, 0);
        __syncthreads();
        if (in1) xstore(As, tid, a1);
        a1 = a2;
        __syncthreads();
    }
    // epilogue: + gcn_b -> mid[b][node][g]
    bf16_t* outb = mid + (size_t)b * NODES * NFEAT;
#pragma unroll
    for (int j = 0; j < 4; j++) {
        int g = n0 + wn * 64 + j * 16 + l15;
        float bias = gcn_b[g];
#pragma unroll
        for (int i = 0; i < 4; i++)
#pragma unroll
            for (int r = 0; r < 4; r++) {
                int node = wm * 64 + i * 16 + q * 4 + r;
                outb[(size_t)node * NFEAT + g] = (bf16_t)(acc2[i][j][r] + bias);
            }
    }
}

// ---- stage 3: split-K=128, BK=64, atomic accumulate into out slot 0 ----
__global__ __launch_bounds__(256, 3)
void k_out(const bf16_t* __restrict__ flat, const float* __restrict__ fcw,
           float* __restrict__ out) {
    __shared__ __align__(16) bf16_t As[TILE * LDK2];  // 18.4 KB
    __shared__ __align__(16) bf16_t Bs[TILE * LDK2];  // 18.4 KB
    const int m0 = blockIdx.x * TILE;
    const int n0 = blockIdx.y * TILE;
    const int kb = blockIdx.z * KCH, kend = kb + KCH;   // 4 iters of BK2
    const int tid = threadIdx.x;
    const int lane = tid & 63, w = tid >> 6, wm = w & 1, wn = w >> 1;
    const int l15 = lane & 15, q = lane >> 4;
    f32x4 acc[4][4] = {};
    const bf16_t* fa = flat + (size_t)m0 * KTOT;
    const float*  fb = fcw + (size_t)n0 * KTOT;

    AT2 at; aload2(fa, KTOT, kb, tid, at);
    XT2 bt; xload2(fb, KTOT, kb, tid, bt);
    astore2(As, tid, at);
    xstore2(Bs, tid, bt);
    __syncthreads();
    for (int k0 = kb; k0 < kend; k0 += BK2) {
        const int kn = k0 + BK2;
        const bool in = kn < kend;
        AT2 an; XT2 bn;
        if (in) { aload2(fa, KTOT, kn, tid, an); xload2(fb, KTOT, kn, tid, bn); }
#pragma unroll
        for (int kk = 0; kk < BK2; kk += BK) {
            bf16x8 a[4], bbf[4];
#pragma unroll
            for (int i = 0; i < 4; i++)
                a[i] = *(const bf16x8*)(As + (wm * 64 + i * 16 + l15) * LDK2 + kk + q * 8);
#pragma unroll
            for (int j = 0; j < 4; j++)
                bbf[j] = *(const bf16x8*)(Bs + (wn * 64 + j * 16 + l15) * LDK2 + kk + q * 8);
#pragma unroll
            for (int i = 0; i < 4; i++)
#pragma unroll
                for (int j = 0; j < 4; j++)
                    acc[i][j] = __builtin_amdgcn_mfma_f32_16x16x32_bf16(a[i], bbf[j], acc[i][j], 0, 0, 0);
        }
        __syncthreads();
        if (in) { astore2(As, tid, an); xstore2(Bs, tid, bn); }
        __syncthreads();
    }
    // atomic accumulate into out slot 0
#pragma unroll
    for (int i = 0; i < 4; i++)
#pragma unroll
        for (int j = 0; j < 4; j++)
#pragma unroll
            for (int r = 0; r < 4; r++) {
                int bt_ = m0 + wm * 64 + i * 16 + q * 4 + r;
                int o   = n0 + wn * 64 + j * 16 + l15;
                atomicAdd(&out[(size_t)bt_ * NFEAT + o], acc[i][j][r]);
            }
}

extern "C" void kernel_launch(void* const* d_in, const int* in_sizes, int n_in,
                              void* d_out, int out_size, void* d_ws, size_t ws_size,
                              hipStream_t stream) {
    const float* x     = (const float*)d_in[0];
    const float* adj   = (const float*)d_in[1];
    const float* gcn_w = (const float*)d_in[2];
    const float* gcn_b = (const float*)d_in[3];
    const float* fc_w  = (const float*)d_in[4];
    const float* fc_b  = (const float*)d_in[5];
    float* out = (float*)d_out;

    // ws: wT 128KB | mid 33.5MB   (part eliminated)
    bf16_t* wT  = (bf16_t*)d_ws;
    bf16_t* mid = (bf16_t*)((char*)d_ws + 131072);

    k_wt     <<<dim3(64), dim3(256), 0, stream>>>(gcn_w, wT);
    k_init   <<<dim3(BATCH), dim3(256), 0, stream>>>(fc_b, x, out);
    k_fused12<<<dim3(2, BATCH), dim3(256), 0, stream>>>(x, adj, wT, gcn_b, mid);
    k_out    <<<dim3(4, 2, SPLIT), dim3(256), 0, stream>>>(mid, fc_w, out);
    k_fin    <<<dim3(BATCH), dim3(256), 0, stream>>>(out);
}

// Round 6
// 203.706 us; speedup vs baseline: 1.1728x; 1.1728x over previous
//
#include <hip/hip_runtime.h>

#define NODES 128
#define NFEAT 256
#define BATCH 512
#define KTOT  (NODES * NFEAT)   // 32768, stage-3 K
#define SPLIT 64                // stage-3 split-K factor
#define KCH   (KTOT / SPLIT)    // 512 per chunk

typedef __bf16 bf16_t;
typedef bf16_t bf16x8 __attribute__((ext_vector_type(8)));
typedef float  f32x4  __attribute__((ext_vector_type(4)));

#define BK    32
#define LDK   40     // bf16 LDS row stride, 32-wide tiles (80B)
#define BK2   64
#define LDK2  72     // bf16 LDS row stride, 64-wide tiles (144B)
#define LDM   136    // Sb row stride
#define TILE  128

// Workgroup barrier WITHOUT the vmcnt(0) drain __syncthreads() emits.
// Only LDS (lgkmcnt) visibility is required across these barriers; global
// prefetch loads stay in flight. No global stores occur inside the K-loops.
__device__ __forceinline__ void bar() {
    asm volatile("s_waitcnt lgkmcnt(0)\n\ts_barrier" ::: "memory");
}

__device__ __forceinline__ bf16x8 cvt8(const float4 a, const float4 b) {
    bf16x8 t;
    t[0] = (bf16_t)a.x; t[1] = (bf16_t)a.y; t[2] = (bf16_t)a.z; t[3] = (bf16_t)a.w;
    t[4] = (bf16_t)b.x; t[5] = (bf16_t)b.y; t[6] = (bf16_t)b.z; t[7] = (bf16_t)b.w;
    return t;
}

// ---- fp32 128x32 tile: reg-load / LDS-store ----
struct XT { float4 v[4]; };
__device__ __forceinline__ void xload(const float* __restrict__ src, int ld, int k0,
                                      int tid, XT& t) {
#pragma unroll
    for (int i = 0; i < 2; i++) {
        int f = tid + i * 256, r = f >> 2, c = f & 3;
        t.v[2 * i]     = *(const float4*)(src + (size_t)r * ld + k0 + c * 8);
        t.v[2 * i + 1] = *(const float4*)(src + (size_t)r * ld + k0 + c * 8 + 4);
    }
}
__device__ __forceinline__ void xstore(bf16_t* __restrict__ dst, int tid, const XT& t) {
#pragma unroll
    for (int i = 0; i < 2; i++) {
        int f = tid + i * 256, r = f >> 2, c = f & 3;
        *(bf16x8*)(dst + r * LDK + c * 8) = cvt8(t.v[2 * i], t.v[2 * i + 1]);
    }
}

// ---- fp32 128x64 tile (k_out B) ----
struct XT2 { float4 v[8]; };
__device__ __forceinline__ void xload2(const float* __restrict__ src, int ld, int k0,
                                       int tid, XT2& t) {
#pragma unroll
    for (int i = 0; i < 4; i++) {
        int f = tid + i * 256, r = f >> 3, c = f & 7;
        t.v[2 * i]     = *(const float4*)(src + (size_t)r * ld + k0 + c * 8);
        t.v[2 * i + 1] = *(const float4*)(src + (size_t)r * ld + k0 + c * 8 + 4);
    }
}
__device__ __forceinline__ void xstore2(bf16_t* __restrict__ dst, int tid, const XT2& t) {
#pragma unroll
    for (int i = 0; i < 4; i++) {
        int f = tid + i * 256, r = f >> 3, c = f & 7;
        *(bf16x8*)(dst + r * LDK2 + c * 8) = cvt8(t.v[2 * i], t.v[2 * i + 1]);
    }
}

// ---- bf16 128x64 tile (k_out A) ----
struct AT2 { bf16x8 v[4]; };
__device__ __forceinline__ void aload2(const bf16_t* __restrict__ src, int ld, int k0,
                                       int tid, AT2& t) {
#pragma unroll
    for (int i = 0; i < 4; i++) {
        int f = tid + i * 256, r = f >> 3, c = f & 7;
        t.v[i] = *(const bf16x8*)(src + (size_t)r * ld + k0 + c * 8);
    }
}
__device__ __forceinline__ void astore2(bf16_t* __restrict__ dst, int tid, const AT2& t) {
#pragma unroll
    for (int i = 0; i < 4; i++) {
        int f = tid + i * 256, r = f >> 3, c = f & 7;
        *(bf16x8*)(dst + r * LDK2 + c * 8) = t.v[i];
    }
}

// ---- pre-transpose gcn_w[k][g] -> wT[g][k] bf16 ----
__global__ __launch_bounds__(256)
void k_wt(const float* __restrict__ w, bf16_t* __restrict__ wT) {
    const int g0 = blockIdx.x * 4;
    const int k  = threadIdx.x;
    const float4 v = *(const float4*)(w + (size_t)k * NFEAT + g0);
    wT[(size_t)(g0 + 0) * NFEAT + k] = (bf16_t)v.x;
    wT[(size_t)(g0 + 1) * NFEAT + k] = (bf16_t)v.y;
    wT[(size_t)(g0 + 2) * NFEAT + k] = (bf16_t)v.z;
    wT[(size_t)(g0 + 3) * NFEAT + k] = (bf16_t)v.w;
}

// ---- fused stages 1+2: dist-2 reg prefetch, custom barriers, 3 blocks/CU ----
__global__ __launch_bounds__(256, 3)
void k_fused12(const float* __restrict__ x, const float* __restrict__ adj,
               const bf16_t* __restrict__ wT, const float* __restrict__ gcn_b,
               bf16_t* __restrict__ mid) {
    __shared__ __align__(16) bf16_t As[TILE * LDK];   // 10.2 KB
    __shared__ __align__(16) bf16_t Sb[TILE * LDM];   // 34.8 KB
    const int n0  = blockIdx.x * TILE;   // g-tile (0 or 128)
    const int b   = blockIdx.y;
    const int tid = threadIdx.x;
    const int lane = tid & 63, w = tid >> 6, wm = w & 1, wn = w >> 1;
    const int l15 = lane & 15, q = lane >> 4;
    const float* xb   = x   + (size_t)b * NODES * NFEAT;
    const float* adjb = adj + (size_t)b * NODES * NODES;

    const bf16_t* wrow[4];
#pragma unroll
    for (int j = 0; j < 4; j++)
        wrow[j] = wT + (size_t)(n0 + wn * 64 + j * 16 + l15) * NFEAT + q * 8;

    // ---- stage 1: S = x[b] @ W  (K=256, 8 iters, dist-2) ----
    f32x4 acc[4][4] = {};
    {
        XT r0, rn, r2;
        xload(xb, NFEAT, 0, tid, r0);
        xload(xb, NFEAT, BK, tid, rn);
        bf16x8 bcur[4], bnxt[4];
#pragma unroll
        for (int j = 0; j < 4; j++) bcur[j] = *(const bf16x8*)(wrow[j]);
        xstore(As, tid, r0);
        bar();
        for (int k0 = 0; k0 < NFEAT; k0 += BK) {
            const bool in1 = (k0 + BK)   < NFEAT;
            const bool in2 = (k0 + 2*BK) < NFEAT;
            if (in2) xload(xb, NFEAT, k0 + 2*BK, tid, r2);   // HBM, 2 iters out
            const int knc = in1 ? k0 + BK : 0;
#pragma unroll
            for (int j = 0; j < 4; j++) bnxt[j] = *(const bf16x8*)(wrow[j] + knc);
            bf16x8 a[4];
#pragma unroll
            for (int i = 0; i < 4; i++)
                a[i] = *(const bf16x8*)(As + (wm * 64 + i * 16 + l15) * LDK + q * 8);
#pragma unroll
            for (int i = 0; i < 4; i++)
#pragma unroll
                for (int j = 0; j < 4; j++)
                    acc[i][j] = __builtin_amdgcn_mfma_f32_16x16x32_bf16(a[i], bcur[j], acc[i][j], 0, 0, 0);
            bar();
            if (in1) xstore(As, tid, rn);
            rn = r2;
#pragma unroll
            for (int j = 0; j < 4; j++) bcur[j] = bnxt[j];
            bar();
        }
    }

    // stage-2 tiles 0,1 in flight while writing Sb
    XT a0, a1, a2;
    xload(adjb, NODES, 0, tid, a0);
    xload(adjb, NODES, BK, tid, a1);
#pragma unroll
    for (int i = 0; i < 4; i++)
#pragma unroll
        for (int j = 0; j < 4; j++)
#pragma unroll
            for (int r = 0; r < 4; r++) {
                int m = wm * 64 + i * 16 + q * 4 + r;
                int g = wn * 64 + j * 16 + l15;
                Sb[g * LDM + m] = (bf16_t)acc[i][j][r];
            }
    bar();                           // stage-1 As reads done + Sb visible
    xstore(As, tid, a0);
    bar();

    // ---- stage 2: mid = adj[b] @ S  (K=128, 4 iters, dist-2) ----
    f32x4 acc2[4][4] = {};
    for (int k0 = 0; k0 < NODES; k0 += BK) {
        const bool in1 = (k0 + BK)   < NODES;
        const bool in2 = (k0 + 2*BK) < NODES;
        if (in2) xload(adjb, NODES, k0 + 2*BK, tid, a2);
        bf16x8 a[4], bb[4];
#pragma unroll
        for (int i = 0; i < 4; i++)
            a[i] = *(const bf16x8*)(As + (wm * 64 + i * 16 + l15) * LDK + q * 8);
#pragma unroll
        for (int j = 0; j < 4; j++)
            bb[j] = *(const bf16x8*)(Sb + (wn * 64 + j * 16 + l15) * LDM + k0 + q * 8);
#pragma unroll
        for (int i = 0; i < 4; i++)
#pragma unroll
            for (int j = 0; j < 4; j++)
                acc2[i][j] = __builtin_amdgcn_mfma_f32_16x16x32_bf16(a[i], bb[j], acc2[i][j], 0, 0, 0);
        bar();
        if (in1) xstore(As, tid, a1);
        a1 = a2;
        bar();
    }
    // epilogue: + gcn_b -> mid[b][node][g]
    bf16_t* outb = mid + (size_t)b * NODES * NFEAT;
#pragma unroll
    for (int j = 0; j < 4; j++) {
        int g = n0 + wn * 64 + j * 16 + l15;
        float bias = gcn_b[g];
#pragma unroll
        for (int i = 0; i < 4; i++)
#pragma unroll
            for (int r = 0; r < 4; r++) {
                int node = wm * 64 + i * 16 + q * 4 + r;
                outb[(size_t)node * NFEAT + g] = (bf16_t)(acc2[i][j][r] + bias);
            }
    }
}

// ---- stage 3: split-K=64, BK=64, custom barriers, bf16 partials ----
__global__ __launch_bounds__(256, 3)
void k_out(const bf16_t* __restrict__ flat, const float* __restrict__ fcw,
           bf16_t* __restrict__ part) {
    __shared__ __align__(16) bf16_t As[TILE * LDK2];  // 18.4 KB
    __shared__ __align__(16) bf16_t Bs[TILE * LDK2];  // 18.4 KB
    const int m0 = blockIdx.x * TILE;
    const int n0 = blockIdx.y * TILE;
    const int kb = blockIdx.z * KCH, kend = kb + KCH;   // 8 iters of BK2
    const int tid = threadIdx.x;
    const int lane = tid & 63, w = tid >> 6, wm = w & 1, wn = w >> 1;
    const int l15 = lane & 15, q = lane >> 4;
    f32x4 acc[4][4] = {};
    const bf16_t* fa = flat + (size_t)m0 * KTOT;
    const float*  fb = fcw + (size_t)n0 * KTOT;

    AT2 at; aload2(fa, KTOT, kb, tid, at);
    XT2 bt; xload2(fb, KTOT, kb, tid, bt);
    astore2(As, tid, at);
    xstore2(Bs, tid, bt);
    bar();
    for (int k0 = kb; k0 < kend; k0 += BK2) {
        const int kn = k0 + BK2;
        const bool in = kn < kend;
        AT2 an; XT2 bn;
        if (in) { aload2(fa, KTOT, kn, tid, an); xload2(fb, KTOT, kn, tid, bn); }
#pragma unroll
        for (int kk = 0; kk < BK2; kk += BK) {
            bf16x8 a[4], bbf[4];
#pragma unroll
            for (int i = 0; i < 4; i++)
                a[i] = *(const bf16x8*)(As + (wm * 64 + i * 16 + l15) * LDK2 + kk + q * 8);
#pragma unroll
            for (int j = 0; j < 4; j++)
                bbf[j] = *(const bf16x8*)(Bs + (wn * 64 + j * 16 + l15) * LDK2 + kk + q * 8);
#pragma unroll
            for (int i = 0; i < 4; i++)
#pragma unroll
                for (int j = 0; j < 4; j++)
                    acc[i][j] = __builtin_amdgcn_mfma_f32_16x16x32_bf16(a[i], bbf[j], acc[i][j], 0, 0, 0);
        }
        bar();
        if (in) { astore2(As, tid, an); xstore2(Bs, tid, bn); }
        bar();
    }
    bf16_t* pb = part + (size_t)blockIdx.z * BATCH * NFEAT;
#pragma unroll
    for (int i = 0; i < 4; i++)
#pragma unroll
        for (int j = 0; j < 4; j++)
#pragma unroll
            for (int r = 0; r < 4; r++) {
                int bt_ = m0 + wm * 64 + i * 16 + q * 4 + r;
                int o   = n0 + wn * 64 + j * 16 + l15;
                pb[(size_t)bt_ * NFEAT + o] = (bf16_t)acc[i][j][r];
            }
}

// ---- stage 4: reduce bf16 partials + fc_b -> slots 0,2; x[:,0,:] -> slot 1 ----
__global__ __launch_bounds__(256)
void k_reduce(const bf16_t* __restrict__ part, const float* __restrict__ fc_b,
              const float* __restrict__ x, float* __restrict__ out) {
    const int g8 = (blockIdx.x * 256 + threadIdx.x) * 8;   // 64 blocks
    const int o = g8 & (NFEAT - 1), b = g8 >> 8;
    float s[8];
    const float4 c0 = *(const float4*)(fc_b + o);
    const float4 c1 = *(const float4*)(fc_b + o + 4);
    s[0] = c0.x; s[1] = c0.y; s[2] = c0.z; s[3] = c0.w;
    s[4] = c1.x; s[5] = c1.y; s[6] = c1.z; s[7] = c1.w;
#pragma unroll 8
    for (int i = 0; i < SPLIT; i++) {
        bf16x8 p = *(const bf16x8*)(part + (size_t)i * BATCH * NFEAT + g8);
#pragma unroll
        for (int j = 0; j < 8; j++) s[j] += (float)p[j];
    }
    float4 o0 = make_float4(s[0], s[1], s[2], s[3]);
    float4 o1 = make_float4(s[4], s[5], s[6], s[7]);
    *(float4*)(out + g8)     = o0;
    *(float4*)(out + g8 + 4) = o1;
    *(float4*)(out + 2 * BATCH * NFEAT + g8)     = o0;
    *(float4*)(out + 2 * BATCH * NFEAT + g8 + 4) = o1;
    // slot 1: x[b][0][o..o+7]
    const float4 x0 = *(const float4*)(x + (size_t)b * NODES * NFEAT + o);
    const float4 x1 = *(const float4*)(x + (size_t)b * NODES * NFEAT + o + 4);
    *(float4*)(out + BATCH * NFEAT + g8)     = x0;
    *(float4*)(out + BATCH * NFEAT + g8 + 4) = x1;
}

extern "C" void kernel_launch(void* const* d_in, const int* in_sizes, int n_in,
                              void* d_out, int out_size, void* d_ws, size_t ws_size,
                              hipStream_t stream) {
    const float* x     = (const float*)d_in[0];
    const float* adj   = (const float*)d_in[1];
    const float* gcn_w = (const float*)d_in[2];
    const float* gcn_b = (const float*)d_in[3];
    const float* fc_w  = (const float*)d_in[4];
    const float* fc_b  = (const float*)d_in[5];
    float* out = (float*)d_out;

    // ws: wT 128KB | mid 33.5MB | part (bf16) 16.8MB  => ~50.5 MB
    bf16_t* wT   = (bf16_t*)d_ws;
    bf16_t* mid  = (bf16_t*)((char*)d_ws + 131072);
    bf16_t* part = (bf16_t*)((char*)d_ws + 131072 + (size_t)BATCH * NODES * NFEAT * 2);

    k_wt     <<<dim3(64), dim3(256), 0, stream>>>(gcn_w, wT);
    k_fused12<<<dim3(2, BATCH), dim3(256), 0, stream>>>(x, adj, wT, gcn_b, mid);
    k_out    <<<dim3(4, 2, SPLIT), dim3(256), 0, stream>>>(mid, fc_w, part);
    k_reduce <<<dim3(64), dim3(256), 0, stream>>>(part, fc_b, x, out);
}

// Round 7
// 200.943 us; speedup vs baseline: 1.1889x; 1.0138x over previous
//
#include <hip/hip_runtime.h>

#define NODES 128
#define NFEAT 256
#define BATCH 512
#define KTOT  (NODES * NFEAT)   // 32768, stage-3 K
#define SPLIT 64                // stage-3 split-K factor
#define KCH   (KTOT / SPLIT)    // 512 per chunk

typedef __bf16 bf16_t;
typedef bf16_t bf16x4 __attribute__((ext_vector_type(4)));
typedef bf16_t bf16x8 __attribute__((ext_vector_type(8)));
typedef float  f32x4  __attribute__((ext_vector_type(4)));

#define BK    32
#define LDK   40     // bf16 LDS row stride, 32-wide tiles (80B)
#define BK2   64
#define LDK2  72     // bf16 LDS row stride, 64-wide tiles (144B)
#define TILE  128

// Workgroup barrier WITHOUT the vmcnt(0) drain __syncthreads() emits.
// Only LDS (lgkmcnt) visibility is needed; global prefetch loads stay in flight.
__device__ __forceinline__ void bar() {
    asm volatile("s_waitcnt lgkmcnt(0)\n\ts_barrier" ::: "memory");
}

__device__ __forceinline__ bf16x8 cvt8(const float4 a, const float4 b) {
    bf16x8 t;
    t[0] = (bf16_t)a.x; t[1] = (bf16_t)a.y; t[2] = (bf16_t)a.z; t[3] = (bf16_t)a.w;
    t[4] = (bf16_t)b.x; t[5] = (bf16_t)b.y; t[6] = (bf16_t)b.z; t[7] = (bf16_t)b.w;
    return t;
}

// ---- fp32 128x32 tile: reg-load / LDS-store ----
struct XT { float4 v[4]; };
__device__ __forceinline__ void xload(const float* __restrict__ src, int ld, int k0,
                                      int tid, XT& t) {
#pragma unroll
    for (int i = 0; i < 2; i++) {
        int f = tid + i * 256, r = f >> 2, c = f & 3;
        t.v[2 * i]     = *(const float4*)(src + (size_t)r * ld + k0 + c * 8);
        t.v[2 * i + 1] = *(const float4*)(src + (size_t)r * ld + k0 + c * 8 + 4);
    }
}
__device__ __forceinline__ void xstore(bf16_t* __restrict__ dst, int tid, const XT& t) {
#pragma unroll
    for (int i = 0; i < 2; i++) {
        int f = tid + i * 256, r = f >> 2, c = f & 3;
        *(bf16x8*)(dst + r * LDK + c * 8) = cvt8(t.v[2 * i], t.v[2 * i + 1]);
    }
}

// ---- fp32 128x64 tile (k_out B) ----
struct XT2 { float4 v[8]; };
__device__ __forceinline__ void xload2(const float* __restrict__ src, int ld, int k0,
                                       int tid, XT2& t) {
#pragma unroll
    for (int i = 0; i < 4; i++) {
        int f = tid + i * 256, r = f >> 3, c = f & 7;
        t.v[2 * i]     = *(const float4*)(src + (size_t)r * ld + k0 + c * 8);
        t.v[2 * i + 1] = *(const float4*)(src + (size_t)r * ld + k0 + c * 8 + 4);
    }
}
__device__ __forceinline__ void xstore2(bf16_t* __restrict__ dst, int tid, const XT2& t) {
#pragma unroll
    for (int i = 0; i < 4; i++) {
        int f = tid + i * 256, r = f >> 3, c = f & 7;
        *(bf16x8*)(dst + r * LDK2 + c * 8) = cvt8(t.v[2 * i], t.v[2 * i + 1]);
    }
}

// ---- bf16 128x64 tile (k_out A) ----
struct AT2 { bf16x8 v[4]; };
__device__ __forceinline__ void aload2(const bf16_t* __restrict__ src, int ld, int k0,
                                       int tid, AT2& t) {
#pragma unroll
    for (int i = 0; i < 4; i++) {
        int f = tid + i * 256, r = f >> 3, c = f & 7;
        t.v[i] = *(const bf16x8*)(src + (size_t)r * ld + k0 + c * 8);
    }
}
__device__ __forceinline__ void astore2(bf16_t* __restrict__ dst, int tid, const AT2& t) {
#pragma unroll
    for (int i = 0; i < 4; i++) {
        int f = tid + i * 256, r = f >> 3, c = f & 7;
        *(bf16x8*)(dst + r * LDK2 + c * 8) = t.v[i];
    }
}

// ---- pre-transpose gcn_w[k][g] -> wT[g][k] bf16 ----
__global__ __launch_bounds__(256)
void k_wt(const float* __restrict__ w, bf16_t* __restrict__ wT) {
    const int g0 = blockIdx.x * 4;
    const int k  = threadIdx.x;
    const float4 v = *(const float4*)(w + (size_t)k * NFEAT + g0);
    wT[(size_t)(g0 + 0) * NFEAT + k] = (bf16_t)v.x;
    wT[(size_t)(g0 + 1) * NFEAT + k] = (bf16_t)v.y;
    wT[(size_t)(g0 + 2) * NFEAT + k] = (bf16_t)v.z;
    wT[(size_t)(g0 + 3) * NFEAT + k] = (bf16_t)v.w;
}

// ---- fused stages 1+2: single-barrier dbuf, dist-3 reg pipeline, 3 blk/CU ----
__global__ __launch_bounds__(256, 3)
void k_fused12(const float* __restrict__ x, const float* __restrict__ adj,
               const bf16_t* __restrict__ wT, const float* __restrict__ gcn_b,
               bf16_t* __restrict__ mid) {
    __shared__ __align__(16) bf16_t As[2][TILE * LDK];  // 2 x 10.2 KB
    __shared__ __align__(16) bf16_t Sb[TILE * TILE];    // 32 KB, XOR-swizzled
    const int n0  = blockIdx.x * TILE;   // g-tile (0 or 128)
    const int b   = blockIdx.y;
    const int tid = threadIdx.x;
    const int lane = tid & 63, w = tid >> 6, wm = w & 1, wn = w >> 1;
    const int l15 = lane & 15, q = lane >> 4;
    const float* xb   = x   + (size_t)b * NODES * NFEAT;
    const float* adjb = adj + (size_t)b * NODES * NODES;

    const bf16_t* wrow[4];
#pragma unroll
    for (int j = 0; j < 4; j++)
        wrow[j] = wT + (size_t)(n0 + wn * 64 + j * 16 + l15) * NFEAT + q * 8;

    // ---- stage 1: S = x[b] @ W  (K=256, 8 iters, 1 barrier/iter) ----
    f32x4 acc[4][4] = {};
    {
        XT r[3];
        xload(xb, NFEAT, 0 * BK, tid, r[0]);
        xload(xb, NFEAT, 1 * BK, tid, r[1]);
        xload(xb, NFEAT, 2 * BK, tid, r[2]);
        xstore(As[0], tid, r[0]);       // tile 0 -> buf 0
        bar();
#pragma unroll
        for (int k = 0; k < 8; k++) {
            if (k + 3 < 8) xload(xb, NFEAT, (k + 3) * BK, tid, r[k % 3]);  // dist-3
            bf16x8 bcur[4];
#pragma unroll
            for (int j = 0; j < 4; j++) bcur[j] = *(const bf16x8*)(wrow[j] + k * BK);
            bf16x8 a[4];
#pragma unroll
            for (int i = 0; i < 4; i++)
                a[i] = *(const bf16x8*)(&As[k & 1][(wm * 64 + i * 16 + l15) * LDK + q * 8]);
#pragma unroll
            for (int i = 0; i < 4; i++)
#pragma unroll
                for (int j = 0; j < 4; j++)
                    acc[i][j] = __builtin_amdgcn_mfma_f32_16x16x32_bf16(a[i], bcur[j], acc[i][j], 0, 0, 0);
            if (k + 1 < 8) xstore(As[(k + 1) & 1], tid, r[(k + 1) % 3]); // data 2 iters old
            bar();
        }
    }

    // preload adj tiles 0..2 while writing Sb
    XT r[3];
    xload(adjb, NODES, 0 * BK, tid, r[0]);
    xload(adjb, NODES, 1 * BK, tid, r[1]);
    xload(adjb, NODES, 2 * BK, tid, r[2]);
    // S -> Sb[g][m], XOR chunk swizzle: slot = (m>>3) ^ (g&15)
#pragma unroll
    for (int i = 0; i < 4; i++)
#pragma unroll
        for (int j = 0; j < 4; j++)
#pragma unroll
            for (int rr = 0; rr < 4; rr++) {
                int m = wm * 64 + i * 16 + q * 4 + rr;
                int g = wn * 64 + j * 16 + l15;
                int slot = (m >> 3) ^ (g & 15);
                Sb[g * 128 + slot * 8 + (m & 7)] = (bf16_t)acc[i][j][rr];
            }
    bar();                              // Sb visible; stage-1 As reads done
    xstore(As[0], tid, r[0]);
    bar();

    // ---- stage 2: mid = adj[b] @ S  (K=128, 4 iters, 1 barrier/iter) ----
    f32x4 acc2[4][4] = {};
#pragma unroll
    for (int k = 0; k < 4; k++) {
        if (k + 3 < 4) xload(adjb, NODES, (k + 3) * BK, tid, r[k % 3]);
        bf16x8 a[4], bb[4];
#pragma unroll
        for (int i = 0; i < 4; i++)
            a[i] = *(const bf16x8*)(&As[k & 1][(wm * 64 + i * 16 + l15) * LDK + q * 8]);
#pragma unroll
        for (int j = 0; j < 4; j++) {
            int R = wn * 64 + j * 16 + l15;
            int slot = (k * 4 + q) ^ (R & 15);
            bb[j] = *(const bf16x8*)(&Sb[R * 128 + slot * 8]);
        }
#pragma unroll
        for (int i = 0; i < 4; i++)
#pragma unroll
            for (int j = 0; j < 4; j++)
                acc2[i][j] = __builtin_amdgcn_mfma_f32_16x16x32_bf16(a[i], bb[j], acc2[i][j], 0, 0, 0);
        if (k + 1 < 4) xstore(As[(k + 1) & 1], tid, r[(k + 1) % 3]);
        bar();
    }
    // epilogue: + gcn_b -> mid[b][node][g]
    bf16_t* outb = mid + (size_t)b * NODES * NFEAT;
#pragma unroll
    for (int j = 0; j < 4; j++) {
        int g = n0 + wn * 64 + j * 16 + l15;
        float bias = gcn_b[g];
#pragma unroll
        for (int i = 0; i < 4; i++)
#pragma unroll
            for (int rr = 0; rr < 4; rr++) {
                int node = wm * 64 + i * 16 + q * 4 + rr;
                outb[(size_t)node * NFEAT + g] = (bf16_t)(acc2[i][j][rr] + bias);
            }
    }
}

// ---- stage 3: split-K=64, BK=64, single-barrier dbuf, deep reg pipeline ----
__global__ __launch_bounds__(256, 2)
void k_out(const bf16_t* __restrict__ flat, const float* __restrict__ fcw,
           bf16_t* __restrict__ part) {
    __shared__ __align__(16) bf16_t As[2][TILE * LDK2];  // 2 x 18.4 KB
    __shared__ __align__(16) bf16_t Bs[2][TILE * LDK2];  // 2 x 18.4 KB
    const int m0 = blockIdx.x * TILE;
    const int n0 = blockIdx.y * TILE;
    const int kb = blockIdx.z * KCH;     // 8 iters of BK2
    const int tid = threadIdx.x;
    const int lane = tid & 63, w = tid >> 6, wm = w & 1, wn = w >> 1;
    const int l15 = lane & 15, q = lane >> 4;
    f32x4 acc[4][4] = {};
    const bf16_t* fa = flat + (size_t)m0 * KTOT;
    const float*  fb = fcw + (size_t)n0 * KTOT;

    AT2 ra[3]; XT2 rb[2];
    aload2(fa, KTOT, kb + 0 * BK2, tid, ra[0]);
    xload2(fb, KTOT, kb + 0 * BK2, tid, rb[0]);
    aload2(fa, KTOT, kb + 1 * BK2, tid, ra[1]);
    xload2(fb, KTOT, kb + 1 * BK2, tid, rb[1]);
    aload2(fa, KTOT, kb + 2 * BK2, tid, ra[2]);
    astore2(As[0], tid, ra[0]);
    xstore2(Bs[0], tid, rb[0]);
    bar();
#pragma unroll
    for (int k = 0; k < 8; k++) {
        if (k + 3 < 8) aload2(fa, KTOT, kb + (k + 3) * BK2, tid, ra[k % 3]);   // A dist-3
        if (k + 2 < 8) xload2(fb, KTOT, kb + (k + 2) * BK2, tid, rb[k & 1]);   // B dist-2
#pragma unroll
        for (int kk = 0; kk < BK2; kk += BK) {
            bf16x8 a[4], bbf[4];
#pragma unroll
            for (int i = 0; i < 4; i++)
                a[i] = *(const bf16x8*)(&As[k & 1][(wm * 64 + i * 16 + l15) * LDK2 + kk + q * 8]);
#pragma unroll
            for (int j = 0; j < 4; j++)
                bbf[j] = *(const bf16x8*)(&Bs[k & 1][(wn * 64 + j * 16 + l15) * LDK2 + kk + q * 8]);
#pragma unroll
            for (int i = 0; i < 4; i++)
#pragma unroll
                for (int j = 0; j < 4; j++)
                    acc[i][j] = __builtin_amdgcn_mfma_f32_16x16x32_bf16(a[i], bbf[j], acc[i][j], 0, 0, 0);
        }
        if (k + 1 < 8) {
            astore2(As[(k + 1) & 1], tid, ra[(k + 1) % 3]);
            xstore2(Bs[(k + 1) & 1], tid, rb[(k + 1) & 1]);
        }
        bar();
    }
    bf16_t* pb = part + (size_t)blockIdx.z * BATCH * NFEAT;
#pragma unroll
    for (int i = 0; i < 4; i++)
#pragma unroll
        for (int j = 0; j < 4; j++)
#pragma unroll
            for (int r = 0; r < 4; r++) {
                int bt_ = m0 + wm * 64 + i * 16 + q * 4 + r;
                int o   = n0 + wn * 64 + j * 16 + l15;
                pb[(size_t)bt_ * NFEAT + o] = (bf16_t)acc[i][j][r];
            }
}

// ---- stage 4: reduce bf16 partials + fc_b -> slots 0,2; x[:,0,:] -> slot 1 ----
__global__ __launch_bounds__(256)
void k_reduce(const bf16_t* __restrict__ part, const float* __restrict__ fc_b,
              const float* __restrict__ x, float* __restrict__ out) {
    const int g4 = (blockIdx.x * 256 + threadIdx.x) * 4;   // 128 blocks
    const int o = g4 & (NFEAT - 1), b = g4 >> 8;
    float s[4];
    const float4 c0 = *(const float4*)(fc_b + o);
    s[0] = c0.x; s[1] = c0.y; s[2] = c0.z; s[3] = c0.w;
#pragma unroll 8
    for (int i = 0; i < SPLIT; i++) {
        bf16x4 p = *(const bf16x4*)(part + (size_t)i * BATCH * NFEAT + g4);
#pragma unroll
        for (int j = 0; j < 4; j++) s[j] += (float)p[j];
    }
    float4 o0 = make_float4(s[0], s[1], s[2], s[3]);
    *(float4*)(out + g4) = o0;
    *(float4*)(out + 2 * BATCH * NFEAT + g4) = o0;
    *(float4*)(out + BATCH * NFEAT + g4) = *(const float4*)(x + (size_t)b * NODES * NFEAT + o);
}

extern "C" void kernel_launch(void* const* d_in, const int* in_sizes, int n_in,
                              void* d_out, int out_size, void* d_ws, size_t ws_size,
                              hipStream_t stream) {
    const float* x     = (const float*)d_in[0];
    const float* adj   = (const float*)d_in[1];
    const float* gcn_w = (const float*)d_in[2];
    const float* gcn_b = (const float*)d_in[3];
    const float* fc_w  = (const float*)d_in[4];
    const float* fc_b  = (const float*)d_in[5];
    float* out = (float*)d_out;

    // ws: wT 128KB | mid 33.5MB | part (bf16) 16.8MB  => ~50.5 MB
    bf16_t* wT   = (bf16_t*)d_ws;
    bf16_t* mid  = (bf16_t*)((char*)d_ws + 131072);
    bf16_t* part = (bf16_t*)((char*)d_ws + 131072 + (size_t)BATCH * NODES * NFEAT * 2);

    k_wt     <<<dim3(64), dim3(256), 0, stream>>>(gcn_w, wT);
    k_fused12<<<dim3(2, BATCH), dim3(256), 0, stream>>>(x, adj, wT, gcn_b, mid);
    k_out    <<<dim3(4, 2, SPLIT), dim3(256), 0, stream>>>(mid, fc_w, part);
    k_reduce <<<dim3(128), dim3(256), 0, stream>>>(part, fc_b, x, out);
}